// Round 3
// baseline (390.432 us; speedup 1.0000x reference)
//
#include <hip/hip_runtime.h>

typedef float v2f __attribute__((ext_vector_type(2)));
typedef float v4f __attribute__((ext_vector_type(4)));

#define N_ROWS 131072
#define DIM    256
#define KP     16
#define NDOM   8
#define NB     32      // bins
#define GG     100     // barycenter grid
#define EBS    36      // padded LDS stride for 33 edges (16B-aligned rows)

#define BARY_SZ (KP*GG)            // 1600

#define GRID   1024
#define WAVES  4
#define NWAVE  (GRID*WAVES)        // 4096 waves
#define ITERS  (N_ROWS/NWAVE)      // 32 rows per wave, exact

__device__ __forceinline__ void pk_fma(v2f &d, v2f a, v2f b) {
    asm("v_pk_fma_f32 %0, %1, %2, %0" : "+v"(d) : "v"(a), "v"(b));
}

__device__ __forceinline__ void wave_fence() {
    // wave-local LDS visibility: lockstep lanes + drained LDS queue.
    asm volatile("s_waitcnt lgkmcnt(0)" ::: "memory");
    __builtin_amdgcn_sched_barrier(0);  // rule #18: pin following ops behind the wait
}

__global__ __launch_bounds__(256, 4)
void inb_kernel(const float* __restrict__ X, const int* __restrict__ y,
                const float* __restrict__ wT, const float* __restrict__ be,
                const float* __restrict__ cv, const float* __restrict__ bq,
                float* __restrict__ out)
{
    // LDS budget: 18432 + 6400 + 8704 + 256 = 33.6 KB -> 4 blocks/CU
    __shared__ alignas(16) float sEB[NDOM*KP*EBS];     // edges, padded stride 36
    __shared__ alignas(16) float sBARY[BARY_SZ];
    __shared__ alignas(16) float sROW[WAVES][2][272];  // double-buffered, g-padded row
    __shared__ alignas(16) float sCOEFF[WAVES][16];

    const int tid = threadIdx.x;
    // stage edges with padded stride (rows stay 16B-aligned for float4 reads)
    for (int i = tid; i < NDOM*KP*(NB+1); i += 256) {
        int p = i / (NB+1), r = i - p*(NB+1);
        sEB[p*EBS + r] = be[i];
    }
    for (int i = tid; i < BARY_SZ; i += 256) sBARY[i] = bq[i];
    __syncthreads();

    const int lane = tid & 63;
    const int wid  = tid >> 6;
    const int k    = lane & 15;   // projection index this lane owns
    const int g    = lane >> 4;   // 64-dim group / 8-edge group this lane owns

    // ---- wT register slices (loop-invariant) ----
    v2f wTp[32];                  // column k, dims [64g, 64g+64)
#pragma unroll
    for (int t2 = 0; t2 < 32; ++t2) {
        int d0 = 64*g + 2*t2;
        v2f w; w[0] = wT[d0*KP + k]; w[1] = wT[(d0+1)*KP + k];
        wTp[t2] = w;
    }
    v2f wTo[4][8];                // rows 4*lane..4*lane+3, all 16 k
#pragma unroll
    for (int j = 0; j < 4; ++j) {
        const v4f* wrow = reinterpret_cast<const v4f*>(&wT[(4*lane + j)*KP]);
#pragma unroll
        for (int q = 0; q < 4; ++q) {
            v4f v = wrow[q];
            v2f a; a[0] = v[0]; a[1] = v[1]; wTo[j][2*q]   = a;
            v2f b; b[0] = v[2]; b[1] = v[3]; wTo[j][2*q+1] = b;
        }
    }

    float (*rowbuf)[272] = sROW[wid];
    float* cobuf  = sCOEFF[wid];
    const int gwave = blockIdx.x * WAVES + wid;
    const int widx  = 68*g + 4*k;            // padded LDS row index

    // prefetch distance 2 on X, distance 1 on y
    v4f x_cur = __builtin_nontemporal_load(
        reinterpret_cast<const v4f*>(&X[(size_t)gwave*DIM + 4*lane]));
    v4f x_nxt = __builtin_nontemporal_load(
        reinterpret_cast<const v4f*>(&X[(size_t)(gwave + NWAVE)*DIM + 4*lane]));
    int dom_cur = y[gwave];

    *reinterpret_cast<v4f*>(&rowbuf[0][widx]) = x_cur;
    wave_fence();

    for (int it = 0; it < ITERS; ++it) {
        const int row = gwave + it*NWAVE;
        const int cur = it & 1;

        // ---- edge loads: depend only on prefetched dom -> issue before proj ----
        const float* ebRow = &sEB[(dom_cur*KP + k)*EBS];
        v4f e0 = *reinterpret_cast<const v4f*>(&ebRow[8*g]);
        v4f e1 = *reinterpret_cast<const v4f*>(&ebRow[8*g + 4]);

        // prefetches
        int dom_nxt = (it + 1 < ITERS) ? y[row + NWAVE] : 0;
        v4f x_pf = {0.f,0.f,0.f,0.f};
        if (it + 2 < ITERS)
            x_pf = __builtin_nontemporal_load(
                reinterpret_cast<const v4f*>(&X[(size_t)(row + 2*NWAVE)*DIM + 4*lane]));

        // ---- projection: p = dot(X[row][64g..64g+63], wT[.,k]) ----
        v2f acc0 = {0.f,0.f}, acc1 = {0.f,0.f};
#pragma unroll
        for (int t = 0; t < 16; ++t) {
            v4f xv = *reinterpret_cast<const v4f*>(&rowbuf[cur][68*g + 4*t]);
            v2f lo; lo[0] = xv[0]; lo[1] = xv[1];
            v2f hi; hi[0] = xv[2]; hi[1] = xv[3];
            pk_fma(acc0, lo, wTp[2*t]);
            pk_fma(acc1, hi, wTp[2*t+1]);
        }

        // stage next row into the other buffer (fenced at end of this iter)
        if (it + 1 < ITERS)
            *reinterpret_cast<v4f*>(&rowbuf[cur^1][widx]) = x_nxt;

        float p = acc0[0] + acc0[1] + acc1[0] + acc1[1];
        p += __shfl_xor(p, 16);
        p += __shfl_xor(p, 32);   // all lanes hold Xm[row][k]
        const float xm = p;

        // ---- count-based searchsorted over edges 0..31 (8 per g-lane) ----
        int cnt = (e0[0] <= xm) + (e0[1] <= xm) + (e0[2] <= xm) + (e0[3] <= xm)
                + (e1[0] <= xm) + (e1[1] <= xm) + (e1[2] <= xm) + (e1[3] <= xm);
        cnt += __shfl_xor(cnt, 16);
        cnt += __shfl_xor(cnt, 32);          // total count of edges[0..31] <= xm
        int i0 = min(max(cnt - 1, 0), NB - 1);

        // one dependent load step: edges from LDS, cdf from L2 (in parallel)
        float x0 = ebRow[i0], x1 = ebRow[i0+1];
        const float* cfRow = cv + (size_t)(dom_cur*KP + k)*(NB+1);
        float f0 = cfRow[i0], f1 = cfRow[i0+1];

        float t  = fminf(fmaxf(__fdividef(xm - x0, x1 - x0), 0.f), 1.f);
        float u  = f0 + t * (f1 - f0);
        float posv = fminf(fmaxf(u, 0.f), 1.f) * (float)(GG - 1);
        int jj = min((int)posv, GG - 2);
        float ttf = posv - (float)jj;
        const float* bqk = &sBARY[k*GG];
        float b0 = bqk[jj], b1 = bqk[jj+1];
        float z = b0*(1.f - ttf) + b1*ttf;
        float coeff = xm - z;                 // out = X - coeff @ wT.T

        if (g == 0) cobuf[k] = coeff;
        wave_fence();   // single fence: covers cobuf write AND next-row staging

        // ---- output: out[d] = x[d] - sum_k coeff[k]*wT[d][k], d = 4*lane+j ----
        v2f c2[8];
#pragma unroll
        for (int q = 0; q < 4; ++q) {
            v4f cv4 = *reinterpret_cast<const v4f*>(&cobuf[4*q]);
            v2f a; a[0] = cv4[0]; a[1] = cv4[1]; c2[2*q]   = a;
            v2f b; b[0] = cv4[2]; b[1] = cv4[3]; c2[2*q+1] = b;
        }
        const float xr[4] = {x_cur[0], x_cur[1], x_cur[2], x_cur[3]};
        float od[4];
#pragma unroll
        for (int j = 0; j < 4; ++j) {
            v2f a = {0.f,0.f};
#pragma unroll
            for (int q = 0; q < 8; ++q) pk_fma(a, c2[q], wTo[j][q]);
            od[j] = xr[j] - (a[0] + a[1]);
        }
        v4f o4; o4[0] = od[0]; o4[1] = od[1]; o4[2] = od[2]; o4[3] = od[3];
        __builtin_nontemporal_store(o4,
            reinterpret_cast<v4f*>(&out[(size_t)row*DIM + 4*lane]));

        x_cur = x_nxt; x_nxt = x_pf; dom_cur = dom_nxt;
    }
}

extern "C" void kernel_launch(void* const* d_in, const int* in_sizes, int n_in,
                              void* d_out, int out_size, void* d_ws, size_t ws_size,
                              hipStream_t stream) {
    const float* X  = (const float*)d_in[0];
    const int*   y  = (const int*)  d_in[1];
    const float* wT = (const float*)d_in[2];
    const float* be = (const float*)d_in[3];
    const float* cv = (const float*)d_in[4];
    const float* bq = (const float*)d_in[5];
    float* out = (float*)d_out;
    hipLaunchKernelGGL(inb_kernel, dim3(GRID), dim3(256), 0, stream,
                       X, y, wT, be, cv, bq, out);
}

// Round 4
// 84.846 us; speedup vs baseline: 4.6017x; 4.6017x over previous
//
#include <hip/hip_runtime.h>

typedef float v2f __attribute__((ext_vector_type(2)));
typedef float v4f __attribute__((ext_vector_type(4)));

#define N_ROWS 131072
#define DIM    256
#define KP     16
#define NDOM   8
#define NB     32      // bins
#define GG     100     // barycenter grid

#define EB_N   (NDOM*KP*(NB+1))   // 4224 floats (stride 33, unpadded)
#define BARY_N (KP*GG)            // 1600

#define GRID   1024
#define WAVES  4
#define NWAVE  (GRID*WAVES)       // 4096 waves
#define ITERS  (N_ROWS/NWAVE)     // 32 rows per wave, exact

__device__ __forceinline__ void pk_fma(v2f &d, v2f a, v2f b) {
    asm("v_pk_fma_f32 %0, %1, %2, %0" : "+v"(d) : "v"(a), "v"(b));
}
__device__ __forceinline__ v2f shfl2(v2f v, int m) {
    v2f r; r[0] = __shfl_xor(v[0], m); r[1] = __shfl_xor(v[1], m); return r;
}
__device__ __forceinline__ void wave_fence() {
    // wave-local LDS visibility (cobuf): drain LDS queue, pin following ops (rule #18)
    asm volatile("s_waitcnt lgkmcnt(0)" ::: "memory");
    __builtin_amdgcn_sched_barrier(0);
}

__global__ __launch_bounds__(256, 4)
void inb_kernel(const float* __restrict__ X, const int* __restrict__ y,
                const float* __restrict__ wT, const float* __restrict__ be,
                const float* __restrict__ cv, const float* __restrict__ bq,
                float* __restrict__ out)
{
    // LDS: 16896 + 16896 + 6400 + 256 = 40448 B <= 40960 -> 4 blocks/CU
    __shared__ float sEB[EB_N];
    __shared__ float sCDF[EB_N];
    __shared__ float sBARY[BARY_N];
    __shared__ float sCOEFF[WAVES][16];

    const int tid = threadIdx.x;
    for (int i = tid; i < EB_N; i += 256) { sEB[i] = be[i]; sCDF[i] = cv[i]; }
    for (int i = tid; i < BARY_N; i += 256) sBARY[i] = bq[i];
    __syncthreads();

    const int lane = tid & 63;
    const int wid  = tid >> 6;
    const int k      = 4*(lane >> 4) + (lane & 3);  // this lane's projection index
    const int echunk = (lane >> 2) & 3;             // 8-edge chunk among 4 redundant lanes

    // ---- the ONLY wT register slice: rows 4l..4l+3, all 16 k (64 VGPR) ----
    // serves projection partials AND the output correction GEMM
    v2f wTo[4][8];
#pragma unroll
    for (int j = 0; j < 4; ++j) {
        const v4f* wrow = reinterpret_cast<const v4f*>(&wT[(4*lane + j)*KP]);
#pragma unroll
        for (int q = 0; q < 4; ++q) {
            v4f v = wrow[q];
            v2f a; a[0] = v[0]; a[1] = v[1]; wTo[j][2*q]   = a;
            v2f b; b[0] = v[2]; b[1] = v[3]; wTo[j][2*q+1] = b;
        }
    }

    float* cobuf = sCOEFF[wid];
    const int gwave = blockIdx.x * WAVES + wid;

    // prefetch distance 2 on X, distance 1 on y (plain cached loads)
    v4f x_cur = *reinterpret_cast<const v4f*>(&X[(size_t)gwave*DIM + 4*lane]);
    v4f x_nxt = *reinterpret_cast<const v4f*>(&X[(size_t)(gwave + NWAVE)*DIM + 4*lane]);
    int dom_cur = y[gwave];

    for (int it = 0; it < ITERS; ++it) {
        const int row = gwave + it*NWAVE;

        // ---- edge reads: depend only on prefetched dom -> issue first ----
        // bank = (16*dom + k + 8*echunk + t) % 32: 16 distinct banks per quarter-wave, conflict-free
        const float* ebRow = &sEB[(dom_cur*KP + k)*(NB+1)];
        float e[8];
#pragma unroll
        for (int t = 0; t < 8; ++t) e[t] = ebRow[8*echunk + t];

        // prefetches
        int dom_nxt = (it + 1 < ITERS) ? y[row + NWAVE] : 0;
        v4f x_pf = {0.f,0.f,0.f,0.f};
        if (it + 2 < ITERS)
            x_pf = *reinterpret_cast<const v4f*>(&X[(size_t)(row + 2*NWAVE)*DIM + 4*lane]);

        // ---- projection partials: P[q] = sum_j x[j]*wT[4l+j][2q..2q+1] ----
        v2f P[8];
#pragma unroll
        for (int q = 0; q < 8; ++q) { P[q][0] = 0.f; P[q][1] = 0.f; }
#pragma unroll
        for (int j = 0; j < 4; ++j) {
            v2f xj; xj[0] = x_cur[j]; xj[1] = x_cur[j];
#pragma unroll
            for (int q = 0; q < 8; ++q) pk_fma(P[q], xj, wTo[j][q]);
        }

        // ---- reduce-scatter butterfly: full 64-lane sum, scattered over k ----
        // Step A (xor 32): keep 8 k's. b5=0 keeps k0-7 (P[0..3]), b5=1 keeps k8-15.
        const bool b5 = (lane & 32) != 0;
        v2f Q[4];
#pragma unroll
        for (int r = 0; r < 4; ++r) {
            v2f keep = b5 ? P[r+4] : P[r];
            v2f send = b5 ? P[r]   : P[r+4];
            Q[r] = keep + shfl2(send, 32);
        }
        // Step B (xor 16): keep 4 k's. base k = 8*b5 + 4*b4.
        const bool b4 = (lane & 16) != 0;
        v2f S0, S1;
        {
            v2f keep0 = b4 ? Q[2] : Q[0];
            v2f keep1 = b4 ? Q[3] : Q[1];
            v2f send0 = b4 ? Q[0] : Q[2];
            v2f send1 = b4 ? Q[1] : Q[3];
            S0 = keep0 + shfl2(send0, 16);
            S1 = keep1 + shfl2(send1, 16);
        }
        // Steps C-F (xor 8,4,2,1): plain reduce of the 4-k quad
#pragma unroll
        for (int m = 8; m >= 1; m >>= 1) { S0 += shfl2(S0, m); S1 += shfl2(S1, m); }
        // select element (lane&3) of the quad -> xm for k = 4*(lane>>4)+(lane&3)
        v2f T = (lane & 2) ? S1 : S0;
        const float xm = (lane & 1) ? T[1] : T[0];

        // ---- count-based searchsorted over edges 0..31 (8 per redundant lane) ----
        int cnt = (e[0] <= xm) + (e[1] <= xm) + (e[2] <= xm) + (e[3] <= xm)
                + (e[4] <= xm) + (e[5] <= xm) + (e[6] <= xm) + (e[7] <= xm);
        cnt += __shfl_xor(cnt, 4);
        cnt += __shfl_xor(cnt, 8);           // sum over the 4 lanes sharing k
        int i0 = min(max(cnt - 1, 0), NB - 1);

        // dependent lookups (4-lane broadcast groups)
        float x0 = ebRow[i0], x1 = ebRow[i0+1];
        const float* cfRow = &sCDF[(dom_cur*KP + k)*(NB+1)];
        float f0 = cfRow[i0], f1 = cfRow[i0+1];

        float t  = fminf(fmaxf(__fdividef(xm - x0, x1 - x0), 0.f), 1.f);
        float u  = f0 + t * (f1 - f0);
        float posv = fminf(fmaxf(u, 0.f), 1.f) * (float)(GG - 1);
        int jj = min((int)posv, GG - 2);
        float ttf = posv - (float)jj;
        float b0 = sBARY[k*GG + jj], b1 = sBARY[k*GG + jj + 1];
        float z = b0*(1.f - ttf) + b1*ttf;
        float coeff = xm - z;                 // out = X - coeff @ wT.T

        if ((lane & 12) == 0) cobuf[k] = coeff;   // 16 writer lanes cover k=0..15
        wave_fence();

        // ---- output: out[4l+j] = x[j] - sum_k coeff[k]*wT[4l+j][k] ----
        v2f c2[8];
#pragma unroll
        for (int q = 0; q < 4; ++q) {
            v4f cv4 = *reinterpret_cast<const v4f*>(&cobuf[4*q]);   // broadcast
            v2f a; a[0] = cv4[0]; a[1] = cv4[1]; c2[2*q]   = a;
            v2f b; b[0] = cv4[2]; b[1] = cv4[3]; c2[2*q+1] = b;
        }
        float od[4];
#pragma unroll
        for (int j = 0; j < 4; ++j) {
            v2f a = {0.f,0.f};
#pragma unroll
            for (int q = 0; q < 8; ++q) pk_fma(a, c2[q], wTo[j][q]);
            od[j] = x_cur[j] - (a[0] + a[1]);
        }
        v4f o4; o4[0] = od[0]; o4[1] = od[1]; o4[2] = od[2]; o4[3] = od[3];
        *reinterpret_cast<v4f*>(&out[(size_t)row*DIM + 4*lane]) = o4;

        x_cur = x_nxt; x_nxt = x_pf; dom_cur = dom_nxt;
    }
}

extern "C" void kernel_launch(void* const* d_in, const int* in_sizes, int n_in,
                              void* d_out, int out_size, void* d_ws, size_t ws_size,
                              hipStream_t stream) {
    const float* X  = (const float*)d_in[0];
    const int*   y  = (const int*)  d_in[1];
    const float* wT = (const float*)d_in[2];
    const float* be = (const float*)d_in[3];
    const float* cv = (const float*)d_in[4];
    const float* bq = (const float*)d_in[5];
    float* out = (float*)d_out;
    hipLaunchKernelGGL(inb_kernel, dim3(GRID), dim3(256), 0, stream,
                       X, y, wT, be, cv, bq, out);
}